// Round 3
// baseline (5558.484 us; speedup 1.0000x reference)
//
#include <hip/hip_runtime.h>
#include <math.h>

#define T_ 512
#define B_ 64
#define H_ 512
#define D_ 32
#define G7H (7*H_)          // 3584
#define NBLK 128
#define NTHR 512
#define JPB 4               // hidden channels per block
#define GRPS 8
#define BPG (NBLK/GRPS)     // 16

typedef short bf16x8 __attribute__((ext_vector_type(8)));
typedef float f32x4  __attribute__((ext_vector_type(4)));
typedef unsigned long long u64;

__device__ __forceinline__ unsigned short f2bf(float x) {
    unsigned u = __float_as_uint(x);
    unsigned r = (u + 0x7FFFu + ((u >> 16) & 1u)) >> 16;
    return (unsigned short)r;
}
__device__ __forceinline__ float bf2f(unsigned short s) {
    return __uint_as_float(((unsigned)s) << 16);
}

// ---- P2[type][j][gate(8)] = b_gates + embed@W_x  (pad gate 7 = 0) ----
__global__ void precompute_P2(const float* __restrict__ embed,
                              const float* __restrict__ Wg,
                              const float* __restrict__ bg,
                              float* __restrict__ P2) {
    int idx = blockIdx.x * blockDim.x + threadIdx.x;
    if (idx >= 33 * H_ * 8) return;
    int gate = idx & 7;
    int j    = (idx >> 3) & (H_ - 1);
    int type = idx >> 12;
    float acc = 0.f;
    if (gate < 7) {
        acc = bg[gate * H_ + j];
        #pragma unroll
        for (int d = 0; d < D_; ++d)
            acc += embed[type * D_ + d] * Wg[(size_t)d * G7H + gate * H_ + j];
    }
    P2[idx] = acc;
}

// ---- Wt_hi/lo[n][k] = bf16 hi/lo split of W_h^T ----
__global__ void precompute_Wt(const float* __restrict__ Wg,
                              unsigned short* __restrict__ Wth,
                              unsigned short* __restrict__ Wtl) {
    int idx = blockIdx.x * blockDim.x + threadIdx.x;   // n*512 + k
    if (idx >= G7H * H_) return;
    int k = idx & (H_ - 1);
    int n = idx >> 9;
    float w = Wg[(size_t)(D_ + k) * G7H + n];
    unsigned short hi = f2bf(w);
    Wth[idx] = hi;
    Wtl[idx] = f2bf(w - bf2f(hi));
}

// ---- h buffer 0 init (hi/lo split of h0) ----
__global__ void init_h(const float* __restrict__ h0,
                       unsigned short* __restrict__ hh,
                       unsigned short* __restrict__ hl) {
    int idx = blockIdx.x * blockDim.x + threadIdx.x;
    if (idx >= B_ * H_) return;
    float x = h0[idx];
    unsigned short hi = f2bf(x);
    hh[idx] = hi;
    hl[idx] = f2bf(x - bf2f(hi));
}

// ---- two-level grid barrier, relaxed agent-scope atomics (proven in r2) ----
__device__ __forceinline__ void grid_barrier(int* __restrict__ sync, int t, int grp) {
    __syncthreads();
    if (threadIdx.x == 0) {
        const int s = t & 1;
        int* c1  = sync + grp * 16 + s;
        int* c2  = sync + 128 + s * 16;
        int* gen = sync + 192;
        int old = __hip_atomic_fetch_add(c1, 1, __ATOMIC_RELAXED, __HIP_MEMORY_SCOPE_AGENT);
        bool release = false;
        if (old == BPG - 1) {
            __hip_atomic_store(c1, 0, __ATOMIC_RELAXED, __HIP_MEMORY_SCOPE_AGENT);
            int o2 = __hip_atomic_fetch_add(c2, 1, __ATOMIC_RELAXED, __HIP_MEMORY_SCOPE_AGENT);
            if (o2 == GRPS - 1) {
                __hip_atomic_store(c2, 0, __ATOMIC_RELAXED, __HIP_MEMORY_SCOPE_AGENT);
                asm volatile("s_waitcnt vmcnt(0)" ::: "memory");
                __hip_atomic_store(gen, t + 1, __ATOMIC_RELAXED, __HIP_MEMORY_SCOPE_AGENT);
                release = true;
            }
        }
        if (!release) {
            while (__hip_atomic_load(gen, __ATOMIC_RELAXED, __HIP_MEMORY_SCOPE_AGENT) < t + 1)
                __builtin_amdgcn_s_sleep(1);
        }
    }
    __syncthreads();
}

__device__ __forceinline__ bf16x8 load_frag_agent(const unsigned short* p) {
    u64 x0 = __hip_atomic_load((const u64*)p,     __ATOMIC_RELAXED, __HIP_MEMORY_SCOPE_AGENT);
    u64 x1 = __hip_atomic_load((const u64*)p + 1, __ATOMIC_RELAXED, __HIP_MEMORY_SCOPE_AGENT);
    union { u64 q[2]; bf16x8 v; } u;
    u.q[0] = x0; u.q[1] = x1;
    return u.v;
}

// ---------------- persistent recurrent kernel (MFMA) ----------------
__global__ void __launch_bounds__(NTHR, 2)
hawkes_main(const float* __restrict__ seq_dt, const int* __restrict__ seq_types,
            const float* __restrict__ c0, const float* __restrict__ ct0,
            const float* __restrict__ P2,
            const unsigned short* __restrict__ Wth,
            const unsigned short* __restrict__ Wtl,
            unsigned short* __restrict__ hh,   // 2 x (B_*H_) bf16-hi double buffer
            unsigned short* __restrict__ hl,   // 2 x (B_*H_) bf16-lo
            int* __restrict__ sync,
            float* __restrict__ out) {
    __shared__ f32x4 pcl[4][2][64];     // K-half partial C: [wm][nt][lane]
    __shared__ float gl[64][36];        // g recurrent part: [b][c_local], padded

    const int tid  = threadIdx.x;
    const int w    = tid >> 6;
    const int lane = tid & 63;
    const int wm   = w & 3;             // m-tile (b-range)
    const int kh   = w >> 2;            // K-half
    const int bid  = blockIdx.x;
    const int grp  = bid & 7;
    const int j0   = grp * 64 + (bid >> 3) * JPB;
    const int m0   = wm * 16;

    // ---- one-time: W B-fragments into registers (persistent across t) ----
    // column permutation: c_local = jl*8 + gate (gate 7 = pad)
    bf16x8 Bh[2][8], Bl[2][8];
    {
        const bf16x8 zfrag = {0, 0, 0, 0, 0, 0, 0, 0};
        const int krow = (lane >> 4) << 3;
        #pragma unroll
        for (int nt = 0; nt < 2; ++nt) {
            const int c_local = nt * 16 + (lane & 15);
            const int gate = c_local & 7, jl2 = c_local >> 3;
            const bool pad = (gate == 7);
            const size_t nbase = pad ? 0 : (size_t)(gate * H_ + j0 + jl2) * (size_t)H_;
            #pragma unroll
            for (int kt = 0; kt < 8; ++kt) {
                const int k0 = kh * 256 + kt * 32 + krow;
                bf16x8 vh = *(const bf16x8*)(Wth + nbase + k0);
                bf16x8 vl = *(const bf16x8*)(Wtl + nbase + k0);
                Bh[nt][kt] = pad ? zfrag : vh;
                Bl[nt][kt] = pad ? zfrag : vl;
            }
        }
    }

    // ---- persistent cell state: thread tid<256 owns cell (b=tid>>2, jl=tid&3) ----
    const int eb = tid >> 2, ejl = tid & 3, ej = j0 + ejl;
    float c_s = 0.f, ct_s = 0.f;
    if (tid < 256) {
        c_s  = c0 [eb * H_ + ej];
        ct_s = ct0[eb * H_ + ej];
    }

    const size_t TBH = (size_t)T_ * B_ * H_;
    const int arow = m0 + (lane & 15);
    const int kb0  = kh * 256 + ((lane >> 4) << 3);

    for (int t = 0; t < T_; ++t) {
        const unsigned short* cu_h = hh + (t & 1) * (B_ * H_);
        const unsigned short* cu_l = hl + (t & 1) * (B_ * H_);
        const unsigned short* ph = cu_h + arow * H_ + kb0;
        const unsigned short* pl = cu_l + arow * H_ + kb0;

        // A-fragments (h hi/lo), agent-scope loads (L2-bypass, fresh data)
        bf16x8 Ahf[8], Alf[8];
        #pragma unroll
        for (int kt = 0; kt < 8; ++kt) Ahf[kt] = load_frag_agent(ph + kt * 32);
        #pragma unroll
        for (int kt = 0; kt < 8; ++kt) Alf[kt] = load_frag_agent(pl + kt * 32);

        f32x4 a0 = {0.f, 0.f, 0.f, 0.f}, a1 = {0.f, 0.f, 0.f, 0.f};
        #pragma unroll
        for (int kt = 0; kt < 8; ++kt) {
            a0 = __builtin_amdgcn_mfma_f32_16x16x32_bf16(Ahf[kt], Bh[0][kt], a0, 0, 0, 0);
            a1 = __builtin_amdgcn_mfma_f32_16x16x32_bf16(Ahf[kt], Bh[1][kt], a1, 0, 0, 0);
            a0 = __builtin_amdgcn_mfma_f32_16x16x32_bf16(Alf[kt], Bh[0][kt], a0, 0, 0, 0);
            a1 = __builtin_amdgcn_mfma_f32_16x16x32_bf16(Alf[kt], Bh[1][kt], a1, 0, 0, 0);
            a0 = __builtin_amdgcn_mfma_f32_16x16x32_bf16(Ahf[kt], Bl[0][kt], a0, 0, 0, 0);
            a1 = __builtin_amdgcn_mfma_f32_16x16x32_bf16(Ahf[kt], Bl[1][kt], a1, 0, 0, 0);
        }

        // combine K-halves via LDS
        if (kh == 1) { pcl[wm][0][lane] = a0; pcl[wm][1][lane] = a1; }
        __syncthreads();
        if (kh == 0) {
            f32x4 q0 = pcl[wm][0][lane], q1 = pcl[wm][1][lane];
            a0 += q0; a1 += q1;
            #pragma unroll
            for (int r = 0; r < 4; ++r) {
                const int b_ = m0 + (lane >> 4) * 4 + r;
                gl[b_][lane & 15]      = a0[r];
                gl[b_][16 + (lane & 15)] = a1[r];
            }
        }
        __syncthreads();

        // elementwise gate/state update
        if (tid < 256) {
            const int b = eb;
            const int type = seq_types[t * B_ + b];
            const float dtv = seq_dt[t * B_ + b];
            const float* pr = P2 + ((size_t)type * H_ + ej) * 8;
            float4 pa = *(const float4*)pr;
            float4 pb = *(const float4*)(pr + 4);
            float4 ga = *(const float4*)&gl[b][ejl * 8];
            float4 gb = *(const float4*)&gl[b][ejl * 8 + 4];
            const float g0 = ga.x + pa.x, g1 = ga.y + pa.y, g2 = ga.z + pa.z, g3 = ga.w + pa.w;
            const float g4 = gb.x + pb.x, g5 = gb.y + pb.y, g6 = gb.z + pb.z;

            const float inpt   = 1.f / (1.f + __expf(-g0));
            const float forget = 1.f / (1.f + __expf(-g1));
            const float output = 1.f / (1.f + __expf(-g2));
            const float in_tar = 1.f / (1.f + __expf(-g3));
            const float fg_tar = 1.f / (1.f + __expf(-g4));
            const float z      = tanhf(g5);
            const float y      = 10.f * g6;
            const float decay  = (fmaxf(y, 0.f) + log1pf(__expf(-fabsf(y)))) * 0.1f;

            const float c_i      = forget * c_s + inpt * z;
            const float ctar_new = fg_tar * ct_s + in_tar * z;
            const float c_t      = ctar_new + (c_i - ctar_new) * __expf(-decay * dtv);
            const float h_t      = output * tanhf(c_t);
            c_s  = c_t;
            ct_s = ctar_new;

            const size_t base = (size_t)t * (B_ * H_) + (size_t)b * H_ + ej;
            out[base]           = h_t;
            out[TBH + base]     = output;
            out[2 * TBH + base] = c_i;
            out[3 * TBH + base] = ctar_new;
            out[4 * TBH + base] = decay;

            // pack hi/lo bf16 of h_t, pairwise u32 agent-scope stores
            unsigned hi16 = f2bf(h_t);
            unsigned lo16 = f2bf(h_t - bf2f((unsigned short)hi16));
            unsigned oth = (unsigned)__shfl_down((int)hi16, 1);
            unsigned otl = (unsigned)__shfl_down((int)lo16, 1);
            if ((ejl & 1) == 0) {
                const int widx = (b * H_ + ej) >> 1;
                unsigned* dh = (unsigned*)(hh + ((t + 1) & 1) * (B_ * H_)) + widx;
                unsigned* dl = (unsigned*)(hl + ((t + 1) & 1) * (B_ * H_)) + widx;
                __hip_atomic_store(dh, hi16 | (oth << 16), __ATOMIC_RELAXED, __HIP_MEMORY_SCOPE_AGENT);
                __hip_atomic_store(dl, lo16 | (otl << 16), __ATOMIC_RELAXED, __HIP_MEMORY_SCOPE_AGENT);
            }
        }
        grid_barrier(sync, t, grp);
    }
}

extern "C" void kernel_launch(void* const* d_in, const int* in_sizes, int n_in,
                              void* d_out, int out_size, void* d_ws, size_t ws_size,
                              hipStream_t stream) {
    const float* seq_dt    = (const float*)d_in[0];
    const int*   seq_types = (const int*)  d_in[1];
    const float* embed     = (const float*)d_in[2];
    const float* W_gates   = (const float*)d_in[3];
    const float* b_gates   = (const float*)d_in[4];
    const float* h0        = (const float*)d_in[5];
    const float* c0        = (const float*)d_in[6];
    const float* ct0       = (const float*)d_in[7];
    float* out = (float*)d_out;

    // workspace: P2 | Wt_hi | Wt_lo | hh(2 buf) | hl(2 buf) | sync
    float* P2 = (float*)d_ws;                                   // 33*512*8 f32
    unsigned short* Wth = (unsigned short*)(P2 + 33 * H_ * 8);  // 3584*512
    unsigned short* Wtl = Wth + (size_t)G7H * H_;
    unsigned short* hh  = Wtl + (size_t)G7H * H_;               // 2*B*H
    unsigned short* hl  = hh + 2 * B_ * H_;
    int* sync = (int*)(hl + 2 * B_ * H_);

    hipMemsetAsync(sync, 0, 256 * sizeof(int), stream);
    {
        int total = 33 * H_ * 8;
        precompute_P2<<<(total + 255) / 256, 256, 0, stream>>>(embed, W_gates, b_gates, P2);
    }
    {
        int total = G7H * H_;
        precompute_Wt<<<(total + 255) / 256, 256, 0, stream>>>(W_gates, Wth, Wtl);
    }
    {
        int total = B_ * H_;
        init_h<<<(total + 255) / 256, 256, 0, stream>>>(h0, hh, hl);
    }
    {
        void* args[] = {(void*)&seq_dt, (void*)&seq_types, (void*)&c0, (void*)&ct0,
                        (void*)&P2, (void*)&Wth, (void*)&Wtl, (void*)&hh, (void*)&hl,
                        (void*)&sync, (void*)&out};
        hipLaunchCooperativeKernel((void*)hawkes_main, dim3(NBLK), dim3(NTHR),
                                   args, 0, stream);
    }
}